// Round 1
// baseline (114.837 us; speedup 1.0000x reference)
//
#include <hip/hip_runtime.h>
#include <hip/hip_bf16.h>

typedef __attribute__((ext_vector_type(4))) float f32x4;
typedef __attribute__((ext_vector_type(8))) short bf16x8;
typedef __attribute__((ext_vector_type(8))) unsigned short u16x8;

#define NB 32
#define HH 112
#define WW 112
#define CIN 64
#define COUT 128
#define HOUT 110
#define WOUT 110
// M = NB*HOUT*WOUT = 387200 = 3025 * 128 exactly

__device__ __forceinline__ unsigned short f2bf(float f) {
  // round-to-nearest-even bf16 truncation (inputs are finite normals)
  unsigned int x = __float_as_uint(f);
  x += 0x7fffu + ((x >> 16) & 1u);
  return (unsigned short)(x >> 16);
}

// Prepack kernels (3,3,64,128) fp32 HWIO -> Bt[co][k] bf16, k = (kh*3+kw)*64+ci
__global__ void prepack_b_kernel(const float* __restrict__ kern,
                                 unsigned short* __restrict__ bt) {
  int idx = blockIdx.x * 256 + threadIdx.x;
  if (idx >= 576 * COUT) return;
  int co = idx / 576;
  int k = idx - co * 576;
  bt[idx] = f2bf(kern[k * COUT + co]);
}

template <bool PREPACK>
__global__ __launch_bounds__(512)
void conv_mfma_kernel(const float* __restrict__ x,
                      const void* __restrict__ bsrc,
                      const float* __restrict__ bias,
                      float* __restrict__ out) {
  // Swizzled LDS tiles: As[row 0..127][k 0..63], Bs[col 0..127][k 0..63], bf16.
  // byte_off within 128B row XORed with (row&7)<<4 -> conflict-free b128 r/w.
  __shared__ __align__(16) unsigned short As[128 * 64];
  __shared__ __align__(16) unsigned short Bs[128 * 64];

  const int tid = threadIdx.x;
  const int m0 = blockIdx.x * 128;

  // ---- staging config: thread -> (tile row sr, 16-element chunk sc)
  const int sr = tid >> 2;
  const int sc = tid & 3;
  const int m = m0 + sr;
  const int wo = m % WOUT;
  const int t1 = m / WOUT;
  const int ho = t1 % HOUT;
  const int b = t1 / HOUT;
  const float* xrow = x + (((b * HH) + ho) * WW + wo) * CIN + sc * 16;
  const int swzS = (sr & 7) << 4;
  unsigned short* aw0 = As + sr * 64 + ((((sc * 32) + 0) ^ swzS) >> 1);
  unsigned short* aw1 = As + sr * 64 + ((((sc * 32) + 16) ^ swzS) >> 1);

  const unsigned short* btrow = nullptr;
  unsigned short* bw0 = nullptr;
  unsigned short* bw1 = nullptr;
  if constexpr (PREPACK) {
    btrow = (const unsigned short*)bsrc + sr * 576 + sc * 16;
    bw0 = Bs + sr * 64 + ((((sc * 32) + 0) ^ swzS) >> 1);
    bw1 = Bs + sr * 64 + ((((sc * 32) + 16) ^ swzS) >> 1);
  }
  // fallback direct-B staging coords
  const int bci = tid >> 3;         // ci 0..63
  const int bco = (tid & 7) * 16;   // co chunk

  // ---- compute config: 8 waves = 4(m) x 2(n); wave tile 32x64 = 2x4 frags
  const int lane = tid & 63;
  const int wid = tid >> 6;
  const int wm = wid >> 1;
  const int wn = wid & 1;
  const int l16 = lane & 15;
  const int lk = lane >> 4;
  const int swzR = (l16 & 7) << 4;

  f32x4 acc[2][4];
#pragma unroll
  for (int i = 0; i < 2; ++i)
#pragma unroll
    for (int j = 0; j < 4; ++j)
      acc[i][j] = (f32x4){0.f, 0.f, 0.f, 0.f};

  const unsigned short* ar0 = As + (wm * 32 + 0 + l16) * 64;
  const unsigned short* ar1 = As + (wm * 32 + 16 + l16) * 64;
  const unsigned short* br0 = Bs + (wn * 64 + 0 + l16) * 64;
  const unsigned short* br1 = Bs + (wn * 64 + 16 + l16) * 64;
  const unsigned short* br2 = Bs + (wn * 64 + 32 + l16) * 64;
  const unsigned short* br3 = Bs + (wn * 64 + 48 + l16) * 64;

  for (int kk = 0; kk < 9; ++kk) {
    const int kh = kk / 3;
    const int kw = kk - kh * 3;

    __syncthreads();  // protect LDS from previous iteration's readers

    // ---- stage A: x[b, ho+kh, wo+kw, 0:64] -> As[sr][0:64] (bf16, swizzled)
    {
      const float* src = xrow + (kh * WW + kw) * CIN;
      f32x4 f0 = *(const f32x4*)(src + 0);
      f32x4 f1 = *(const f32x4*)(src + 4);
      f32x4 f2 = *(const f32x4*)(src + 8);
      f32x4 f3 = *(const f32x4*)(src + 12);
      u16x8 v0, v1;
#pragma unroll
      for (int j = 0; j < 4; ++j) {
        v0[j]     = f2bf(f0[j]);
        v0[4 + j] = f2bf(f1[j]);
        v1[j]     = f2bf(f2[j]);
        v1[4 + j] = f2bf(f3[j]);
      }
      *(u16x8*)aw0 = v0;
      *(u16x8*)aw1 = v1;
    }

    // ---- stage B: Bs[co][ci] (bf16, swizzled)
    if constexpr (PREPACK) {
      const u16x8* p = (const u16x8*)(btrow + kk * 64);
      *(u16x8*)bw0 = p[0];
      *(u16x8*)bw1 = p[1];
    } else {
      const float* kern = (const float*)bsrc;
      const float* ks = kern + (kk * 64 + bci) * COUT + bco;
      f32x4 g0 = *(const f32x4*)(ks + 0);
      f32x4 g1 = *(const f32x4*)(ks + 4);
      f32x4 g2 = *(const f32x4*)(ks + 8);
      f32x4 g3 = *(const f32x4*)(ks + 12);
#pragma unroll
      for (int j = 0; j < 4; ++j) {
        int c0 = bco + j;
        Bs[c0 * 64 + (((bci * 2) ^ ((c0 & 7) << 4)) >> 1)] = f2bf(g0[j]);
        int c1 = bco + 4 + j;
        Bs[c1 * 64 + (((bci * 2) ^ ((c1 & 7) << 4)) >> 1)] = f2bf(g1[j]);
        int c2 = bco + 8 + j;
        Bs[c2 * 64 + (((bci * 2) ^ ((c2 & 7) << 4)) >> 1)] = f2bf(g2[j]);
        int c3 = bco + 12 + j;
        Bs[c3 * 64 + (((bci * 2) ^ ((c3 & 7) << 4)) >> 1)] = f2bf(g3[j]);
      }
    }

    __syncthreads();

    // ---- compute: 2 k-steps of 32, 8 MFMA each
#pragma unroll
    for (int ks = 0; ks < 2; ++ks) {
      const int cbs = ((ks * 64 + lk * 16) ^ swzR) >> 1;
      bf16x8 a0 = *(const bf16x8*)(ar0 + cbs);
      bf16x8 a1 = *(const bf16x8*)(ar1 + cbs);
      bf16x8 b0 = *(const bf16x8*)(br0 + cbs);
      bf16x8 b1 = *(const bf16x8*)(br1 + cbs);
      bf16x8 b2 = *(const bf16x8*)(br2 + cbs);
      bf16x8 b3 = *(const bf16x8*)(br3 + cbs);
      acc[0][0] = __builtin_amdgcn_mfma_f32_16x16x32_bf16(a0, b0, acc[0][0], 0, 0, 0);
      acc[0][1] = __builtin_amdgcn_mfma_f32_16x16x32_bf16(a0, b1, acc[0][1], 0, 0, 0);
      acc[0][2] = __builtin_amdgcn_mfma_f32_16x16x32_bf16(a0, b2, acc[0][2], 0, 0, 0);
      acc[0][3] = __builtin_amdgcn_mfma_f32_16x16x32_bf16(a0, b3, acc[0][3], 0, 0, 0);
      acc[1][0] = __builtin_amdgcn_mfma_f32_16x16x32_bf16(a1, b0, acc[1][0], 0, 0, 0);
      acc[1][1] = __builtin_amdgcn_mfma_f32_16x16x32_bf16(a1, b1, acc[1][1], 0, 0, 0);
      acc[1][2] = __builtin_amdgcn_mfma_f32_16x16x32_bf16(a1, b2, acc[1][2], 0, 0, 0);
      acc[1][3] = __builtin_amdgcn_mfma_f32_16x16x32_bf16(a1, b3, acc[1][3], 0, 0, 0);
    }
  }

  // ---- epilogue: bias + relu, C/D layout col=lane&15, row=(lane>>4)*4+reg
  const int ncol = wn * 64 + l16;
  const float bv0 = bias[ncol + 0];
  const float bv1 = bias[ncol + 16];
  const float bv2 = bias[ncol + 32];
  const float bv3 = bias[ncol + 48];
  const int mrow0 = m0 + wm * 32 + lk * 4;
#pragma unroll
  for (int mf = 0; mf < 2; ++mf) {
#pragma unroll
    for (int j = 0; j < 4; ++j) {
      const int row = mrow0 + mf * 16 + j;
      float* orow = out + (size_t)row * COUT + ncol;
      orow[0]  = fmaxf(acc[mf][0][j] + bv0, 0.f);
      orow[16] = fmaxf(acc[mf][1][j] + bv1, 0.f);
      orow[32] = fmaxf(acc[mf][2][j] + bv2, 0.f);
      orow[48] = fmaxf(acc[mf][3][j] + bv3, 0.f);
    }
  }
}

extern "C" void kernel_launch(void* const* d_in, const int* in_sizes, int n_in,
                              void* d_out, int out_size, void* d_ws, size_t ws_size,
                              hipStream_t stream) {
  const float* x = (const float*)d_in[0];
  const float* kern = (const float*)d_in[1];
  const float* bias = (const float*)d_in[2];
  float* out = (float*)d_out;

  const size_t bt_bytes = 576 * COUT * sizeof(unsigned short);
  if (d_ws != nullptr && ws_size >= bt_bytes) {
    unsigned short* bt = (unsigned short*)d_ws;
    prepack_b_kernel<<<288, 256, 0, stream>>>(kern, bt);
    conv_mfma_kernel<true><<<3025, 512, 0, stream>>>(x, (const void*)bt, bias, out);
  } else {
    conv_mfma_kernel<false><<<3025, 512, 0, stream>>>(x, (const void*)kern, bias, out);
  }
}

// Round 3
// 110.351 us; speedup vs baseline: 1.0406x; 1.0406x over previous
//
#include <hip/hip_runtime.h>
#include <hip/hip_bf16.h>

typedef __attribute__((ext_vector_type(4))) float f32x4;
typedef __attribute__((ext_vector_type(8))) short bf16x8;
typedef __attribute__((ext_vector_type(8))) unsigned short u16x8;

#define NB 32
#define HH 112
#define WW 112
#define CIN 64
#define COUT 128
#define HOUT 110
#define WOUT 110
#define NWG 3025  // 387200 / 128

__device__ __forceinline__ unsigned short f2bf(float f) {
  unsigned int x = __float_as_uint(f);
  x += 0x7fffu + ((x >> 16) & 1u);
  return (unsigned short)(x >> 16);
}

// Prepack kernels (3,3,64,128) fp32 HWIO -> Bt[co][k] bf16, k = (kh*3+kw)*64+ci
__global__ void prepack_b_kernel(const float* __restrict__ kern,
                                 unsigned short* __restrict__ bt) {
  int idx = blockIdx.x * 256 + threadIdx.x;
  if (idx >= 576 * COUT) return;
  int co = idx / 576;
  int k = idx - co * 576;
  bt[idx] = f2bf(kern[k * COUT + co]);
}

template <bool PREPACK>
__global__ __launch_bounds__(512)
void conv_mfma_kernel(const float* __restrict__ x,
                      const void* __restrict__ bsrc,
                      const float* __restrict__ bias,
                      float* __restrict__ out) {
  // Double-buffered swizzled LDS: write buf^1 while computing from buf.
  __shared__ __align__(16) unsigned short As[2][128 * 64];
  __shared__ __align__(16) unsigned short Bs[2][128 * 64];

  const int tid = threadIdx.x;
  const int m0 = blockIdx.x * 128;

  // ---- staging config: thread -> (tile row sr, 16-element chunk sc)
  const int sr = tid >> 2;
  const int sc = tid & 3;
  const int m = m0 + sr;
  const int wo = m % WOUT;
  const int t1 = m / WOUT;
  const int ho = t1 % HOUT;
  const int b = t1 / HOUT;
  const float* xrow = x + (((b * HH) + ho) * WW + wo) * CIN + sc * 16;
  const int swzS = (sr & 7) << 4;
  const int awoff0 = sr * 64 + ((((sc * 32) + 0) ^ swzS) >> 1);
  const int awoff1 = sr * 64 + ((((sc * 32) + 16) ^ swzS) >> 1);

  const unsigned short* btrow = nullptr;
  if constexpr (PREPACK) {
    btrow = (const unsigned short*)bsrc + sr * 576 + sc * 16;
  }
  // fallback direct-B staging coords
  const int bci = tid >> 3;
  const int bco = (tid & 7) * 16;

  // ---- compute config: 8 waves = 4(m) x 2(n); wave tile 32x64 = 2x4 frags
  const int lane = tid & 63;
  const int wid = tid >> 6;
  const int wm = wid >> 1;
  const int wn = wid & 1;
  const int l16 = lane & 15;
  const int lk = lane >> 4;
  const int swzR = (l16 & 7) << 4;

  const int aroff0 = (wm * 32 + 0 + l16) * 64;
  const int aroff1 = (wm * 32 + 16 + l16) * 64;
  const int broff0 = (wn * 64 + 0 + l16) * 64;
  const int broff1 = (wn * 64 + 16 + l16) * 64;
  const int broff2 = (wn * 64 + 32 + l16) * 64;
  const int broff3 = (wn * 64 + 48 + l16) * 64;

  f32x4 acc[2][4];
#pragma unroll
  for (int i = 0; i < 2; ++i)
#pragma unroll
    for (int j = 0; j < 4; ++j)
      acc[i][j] = (f32x4){0.f, 0.f, 0.f, 0.f};

  // ---- prologue: load tap 0 and stage into buffer 0
  {
    f32x4 f0 = *(const f32x4*)(xrow + 0);
    f32x4 f1 = *(const f32x4*)(xrow + 4);
    f32x4 f2 = *(const f32x4*)(xrow + 8);
    f32x4 f3 = *(const f32x4*)(xrow + 12);
    u16x8 v0, v1;
#pragma unroll
    for (int j = 0; j < 4; ++j) {
      v0[j]     = f2bf(f0[j]);
      v0[4 + j] = f2bf(f1[j]);
      v1[j]     = f2bf(f2[j]);
      v1[4 + j] = f2bf(f3[j]);
    }
    *(u16x8*)(As[0] + awoff0) = v0;
    *(u16x8*)(As[0] + awoff1) = v1;
    if constexpr (PREPACK) {
      const u16x8* p = (const u16x8*)btrow;
      *(u16x8*)(Bs[0] + awoff0) = p[0];
      *(u16x8*)(Bs[0] + awoff1) = p[1];
    } else {
      const float* kern = (const float*)bsrc;
      const float* kslab = kern + bci * COUT + bco;
      f32x4 g0 = *(const f32x4*)(kslab + 0);
      f32x4 g1 = *(const f32x4*)(kslab + 4);
      f32x4 g2 = *(const f32x4*)(kslab + 8);
      f32x4 g3 = *(const f32x4*)(kslab + 12);
#pragma unroll
      for (int j = 0; j < 4; ++j) {
        int c0 = bco + j;
        Bs[0][c0 * 64 + (((bci * 2) ^ ((c0 & 7) << 4)) >> 1)] = f2bf(g0[j]);
        int c1 = bco + 4 + j;
        Bs[0][c1 * 64 + (((bci * 2) ^ ((c1 & 7) << 4)) >> 1)] = f2bf(g1[j]);
        int c2 = bco + 8 + j;
        Bs[0][c2 * 64 + (((bci * 2) ^ ((c2 & 7) << 4)) >> 1)] = f2bf(g2[j]);
        int c3 = bco + 12 + j;
        Bs[0][c3 * 64 + (((bci * 2) ^ ((c3 & 7) << 4)) >> 1)] = f2bf(g3[j]);
      }
    }
  }

#pragma unroll
  for (int kk = 0; kk < 9; ++kk) {
    const int cur = kk & 1;
    const int nxt = cur ^ 1;

    // ---- issue tap kk+1 global loads; latency hides under compute below
    f32x4 g0, g1, g2, g3;
    u16x8 bq0, bq1;
    if (kk < 8) {
      const int kn = kk + 1;
      const int kh2 = kn / 3;
      const int kw2 = kn - kh2 * 3;
      const float* src = xrow + (kh2 * WW + kw2) * CIN;
      g0 = *(const f32x4*)(src + 0);
      g1 = *(const f32x4*)(src + 4);
      g2 = *(const f32x4*)(src + 8);
      g3 = *(const f32x4*)(src + 12);
      if constexpr (PREPACK) {
        const u16x8* p = (const u16x8*)(btrow + kn * 64);
        bq0 = p[0];
        bq1 = p[1];
      }
    }

    __syncthreads();  // buf[cur] fully staged; prev readers of buf[nxt] done

    // ---- compute from buf[cur]: 2 k-steps of 32, 8 MFMA each
    const unsigned short* Ac = As[cur];
    const unsigned short* Bc = Bs[cur];
#pragma unroll
    for (int ks = 0; ks < 2; ++ks) {
      const int cbs = ((ks * 64 + lk * 16) ^ swzR) >> 1;
      bf16x8 a0 = *(const bf16x8*)(Ac + aroff0 + cbs);
      bf16x8 a1 = *(const bf16x8*)(Ac + aroff1 + cbs);
      bf16x8 b0 = *(const bf16x8*)(Bc + broff0 + cbs);
      bf16x8 b1 = *(const bf16x8*)(Bc + broff1 + cbs);
      bf16x8 b2 = *(const bf16x8*)(Bc + broff2 + cbs);
      bf16x8 b3 = *(const bf16x8*)(Bc + broff3 + cbs);
      acc[0][0] = __builtin_amdgcn_mfma_f32_16x16x32_bf16(a0, b0, acc[0][0], 0, 0, 0);
      acc[0][1] = __builtin_amdgcn_mfma_f32_16x16x32_bf16(a0, b1, acc[0][1], 0, 0, 0);
      acc[0][2] = __builtin_amdgcn_mfma_f32_16x16x32_bf16(a0, b2, acc[0][2], 0, 0, 0);
      acc[0][3] = __builtin_amdgcn_mfma_f32_16x16x32_bf16(a0, b3, acc[0][3], 0, 0, 0);
      acc[1][0] = __builtin_amdgcn_mfma_f32_16x16x32_bf16(a1, b0, acc[1][0], 0, 0, 0);
      acc[1][1] = __builtin_amdgcn_mfma_f32_16x16x32_bf16(a1, b1, acc[1][1], 0, 0, 0);
      acc[1][2] = __builtin_amdgcn_mfma_f32_16x16x32_bf16(a1, b2, acc[1][2], 0, 0, 0);
      acc[1][3] = __builtin_amdgcn_mfma_f32_16x16x32_bf16(a1, b3, acc[1][3], 0, 0, 0);
    }

    // ---- stage tap kk+1 into buf[nxt] (opposite buffer: no addr overlap
    //      with this iteration's reads; next iteration's barrier orders RAW)
    if (kk < 8) {
      u16x8 v0, v1;
#pragma unroll
      for (int j = 0; j < 4; ++j) {
        v0[j]     = f2bf(g0[j]);
        v0[4 + j] = f2bf(g1[j]);
        v1[j]     = f2bf(g2[j]);
        v1[4 + j] = f2bf(g3[j]);
      }
      *(u16x8*)(As[nxt] + awoff0) = v0;
      *(u16x8*)(As[nxt] + awoff1) = v1;
      if constexpr (PREPACK) {
        *(u16x8*)(Bs[nxt] + awoff0) = bq0;
        *(u16x8*)(Bs[nxt] + awoff1) = bq1;
      } else {
        const float* kern = (const float*)bsrc;
        const float* kslab = kern + ((kk + 1) * 64 + bci) * COUT + bco;
        f32x4 h0 = *(const f32x4*)(kslab + 0);
        f32x4 h1 = *(const f32x4*)(kslab + 4);
        f32x4 h2 = *(const f32x4*)(kslab + 8);
        f32x4 h3 = *(const f32x4*)(kslab + 12);
#pragma unroll
        for (int j = 0; j < 4; ++j) {
          int c0 = bco + j;
          Bs[nxt][c0 * 64 + (((bci * 2) ^ ((c0 & 7) << 4)) >> 1)] = f2bf(h0[j]);
          int c1 = bco + 4 + j;
          Bs[nxt][c1 * 64 + (((bci * 2) ^ ((c1 & 7) << 4)) >> 1)] = f2bf(h1[j]);
          int c2 = bco + 8 + j;
          Bs[nxt][c2 * 64 + (((bci * 2) ^ ((c2 & 7) << 4)) >> 1)] = f2bf(h2[j]);
          int c3 = bco + 12 + j;
          Bs[nxt][c3 * 64 + (((bci * 2) ^ ((c3 & 7) << 4)) >> 1)] = f2bf(h3[j]);
        }
      }
    }
  }

  // ---- epilogue: bias + relu, C/D layout col=lane&15, row=(lane>>4)*4+reg
  const int ncol = wn * 64 + l16;
  const float bv0 = bias[ncol + 0];
  const float bv1 = bias[ncol + 16];
  const float bv2 = bias[ncol + 32];
  const float bv3 = bias[ncol + 48];
  const int mrow0 = m0 + wm * 32 + lk * 4;
#pragma unroll
  for (int mf = 0; mf < 2; ++mf) {
#pragma unroll
    for (int j = 0; j < 4; ++j) {
      const int row = mrow0 + mf * 16 + j;
      float* orow = out + (size_t)row * COUT + ncol;
      orow[0]  = fmaxf(acc[mf][0][j] + bv0, 0.f);
      orow[16] = fmaxf(acc[mf][1][j] + bv1, 0.f);
      orow[32] = fmaxf(acc[mf][2][j] + bv2, 0.f);
      orow[48] = fmaxf(acc[mf][3][j] + bv3, 0.f);
    }
  }
}

extern "C" void kernel_launch(void* const* d_in, const int* in_sizes, int n_in,
                              void* d_out, int out_size, void* d_ws, size_t ws_size,
                              hipStream_t stream) {
  const float* x = (const float*)d_in[0];
  const float* kern = (const float*)d_in[1];
  const float* bias = (const float*)d_in[2];
  float* out = (float*)d_out;

  const size_t bt_bytes = 576 * COUT * sizeof(unsigned short);
  if (d_ws != nullptr && ws_size >= bt_bytes) {
    unsigned short* bt = (unsigned short*)d_ws;
    prepack_b_kernel<<<288, 256, 0, stream>>>(kern, bt);
    conv_mfma_kernel<true><<<NWG, 512, 0, stream>>>(x, (const void*)bt, bias, out);
  } else {
    conv_mfma_kernel<false><<<NWG, 512, 0, stream>>>(x, (const void*)kern, bias, out);
  }
}